// Round 3
// baseline (664.228 us; speedup 1.0000x reference)
//
#include <hip/hip_runtime.h>
#include <hip/hip_fp16.h>

#define RES 512
#define CF 32
#define PLANE_ELEMS (RES * RES)          // 262144 per channel-plane
#define TX 128                           // x-span per transpose block

typedef float fvec4 __attribute__((ext_vector_type(4)));   // clang-native, OK for nontemporal builtins

// ---------------------------------------------------------------------------
// Pass 1: transpose C_mat [3][32][512][512] fp32 -> ws [3][512][512][32] fp16
// LDS-tiled: block = (p, y, 128-wide x chunk).
//   Phase 1: float4 global reads, scalar writes into tile[32][129]
//            (bank = (c + x) % 32, <=2-way conflict — free per m136).
//   Phase 2: column reads (<=2-way), cvt fp16, 32B/thread contiguous stores.
// ---------------------------------------------------------------------------
__global__ __launch_bounds__(256) void triplane_transpose(
    const float* __restrict__ C_mat, __half* __restrict__ ws) {
    __shared__ float tile[CF][TX + 1];

    int b  = blockIdx.x;
    int xc = b & 3;
    int y  = (b >> 2) & (RES - 1);
    int p  = b >> 11;
    int x0 = xc * TX;
    int t  = threadIdx.x;

    // Phase 1: load 32 c-rows x 128 x into LDS
    int c = t >> 3;            // 0..31
    int j = t & 7;             // 0..7
    const float* src = C_mat + (((size_t)(p * CF + c)) << 18) + (size_t)y * RES + x0 + j * 4;
#pragma unroll
    for (int k = 0; k < 4; ++k) {
        fvec4 v = *(const fvec4*)(src + k * 32);
        int xl = j * 4 + k * 32;
        tile[c][xl + 0] = v.x;
        tile[c][xl + 1] = v.y;
        tile[c][xl + 2] = v.z;
        tile[c][xl + 3] = v.w;
    }
    __syncthreads();

    // Phase 2: each thread emits half of one 64B record (16 fp16 = 32B)
    int xr = t >> 1;           // 0..127 record within chunk
    int h  = t & 1;            // which 16-channel half
    __half hv[16] __attribute__((aligned(16)));
#pragma unroll
    for (int q = 0; q < 16; ++q) {
        hv[q] = __float2half(tile[h * 16 + q][xr]);
    }
    size_t rec = ((size_t)(p * RES + y) * RES + x0 + xr);
    fvec4* dst = (fvec4*)(ws + rec * CF + h * 16);
    const fvec4* s4 = (const fvec4*)hv;
    dst[0] = s4[0];
    dst[1] = s4[1];
}

// ---------------------------------------------------------------------------
// Pass 2: sample. 4 lanes per point; lane `sub` owns channels [sub*8, sub*8+8).
// All 12 corner offsets computed first, then all 12 16B loads issued
// back-to-back (max MLP), then the weighted accumulation.
// __launch_bounds__(256,4): allow ~128 VGPR so the scheduler keeps the whole
// load batch in flight instead of serializing for occupancy.
// ---------------------------------------------------------------------------
__global__ __launch_bounds__(256, 4) void triplane_sample(
    const float* __restrict__ xin, const __half* __restrict__ planes,
    float* __restrict__ out, int n_pts) {
    int gid = blockIdx.x * 256 + threadIdx.x;
    int n   = gid >> 2;
    int sub = gid & 3;
    if (n >= n_pts) return;

    float cx = __builtin_nontemporal_load(xin + 3 * n + 0);
    float cy = __builtin_nontemporal_load(xin + 3 * n + 1);
    float cz = __builtin_nontemporal_load(xin + 3 * n + 2);
    float gxs[3] = {cx, cx, cy};
    float gys[3] = {cy, cz, cz};

    int   offs[12];   // byte offsets into `planes` (fits in int: < 50MB)
    float wgt[12];

#pragma unroll
    for (int p = 0; p < 3; ++p) {
        float ix = ((gxs[p] + 1.0f) * (float)RES - 1.0f) * 0.5f;
        float iy = ((gys[p] + 1.0f) * (float)RES - 1.0f) * 0.5f;
        float x0f = floorf(ix), y0f = floorf(iy);
        float wx1 = ix - x0f,  wy1 = iy - y0f;
        float wx0 = 1.0f - wx1, wy0 = 1.0f - wy1;
        int x0 = (int)x0f, y0 = (int)y0f;
        int x1 = x0 + 1,   y1 = y0 + 1;

        int   cxs[4] = {x0, x1, x0, x1};
        int   cys[4] = {y0, y0, y1, y1};
        float cws[4] = {wx0 * wy0, wx1 * wy0, wx0 * wy1, wx1 * wy1};
        int pbase = p * (PLANE_ELEMS * CF * 2);   // bytes
#pragma unroll
        for (int cc = 0; cc < 4; ++cc) {
            int xi = cxs[cc], yi = cys[cc];
            bool valid = ((unsigned)xi < (unsigned)RES) & ((unsigned)yi < (unsigned)RES);
            int xcl = min(max(xi, 0), RES - 1);
            int ycl = min(max(yi, 0), RES - 1);
            wgt[p * 4 + cc]  = valid ? cws[cc] : 0.0f;
            offs[p * 4 + cc] = pbase + ((ycl << 9) + xcl) * (CF * 2);
        }
    }

    const char* pb = (const char*)planes + sub * 16;   // this lane's 8 channels
    fvec4 raw[12];
#pragma unroll
    for (int l = 0; l < 12; ++l) {
        raw[l] = *(const fvec4*)(pb + offs[l]);
    }

    float acc[8];
#pragma unroll
    for (int k = 0; k < 8; ++k) acc[k] = 0.0f;

#pragma unroll
    for (int l = 0; l < 12; ++l) {
        const __half2* h2 = (const __half2*)&raw[l];
        float w = wgt[l];
#pragma unroll
        for (int k = 0; k < 4; ++k) {
            float2 f = __half22float2(h2[k]);
            acc[2 * k + 0] += w * f.x;
            acc[2 * k + 1] += w * f.y;
        }
    }

    float* o = out + (size_t)n * CF + (size_t)sub * 8;
    fvec4 o0 = {acc[0], acc[1], acc[2], acc[3]};
    fvec4 o1 = {acc[4], acc[5], acc[6], acc[7]};
    __builtin_nontemporal_store(o0, (fvec4*)o);
    __builtin_nontemporal_store(o1, (fvec4*)(o + 4));
}

// ---------------------------------------------------------------------------
// Fallback: direct fp32 gather from native [3][32][512][512] layout
// (only used if ws_size is too small for the transposed planes).
// ---------------------------------------------------------------------------
__global__ __launch_bounds__(256) void triplane_sample_direct(
    const float* __restrict__ xin, const float* __restrict__ C_mat,
    float* __restrict__ out, int n_pts) {
    int gid = blockIdx.x * 256 + threadIdx.x;
    int n   = gid >> 2;
    int sub = gid & 3;
    if (n >= n_pts) return;

    float coord[3] = {xin[3 * n], xin[3 * n + 1], xin[3 * n + 2]};
    const int ii[3] = {0, 0, 1};
    const int jj[3] = {1, 2, 2};

    float acc[8];
#pragma unroll
    for (int k = 0; k < 8; ++k) acc[k] = 0.0f;

    for (int p = 0; p < 3; ++p) {
        float gx = coord[ii[p]];
        float gy = coord[jj[p]];
        float ix = ((gx + 1.0f) * (float)RES - 1.0f) * 0.5f;
        float iy = ((gy + 1.0f) * (float)RES - 1.0f) * 0.5f;
        float x0f = floorf(ix), y0f = floorf(iy);
        float wx1 = ix - x0f,  wy1 = iy - y0f;
        float wx0 = 1.0f - wx1, wy0 = 1.0f - wy1;
        int x0 = (int)x0f, y0 = (int)y0f;
        int x1 = x0 + 1,   y1 = y0 + 1;

        int   cxs[4] = {x0, x1, x0, x1};
        int   cys[4] = {y0, y0, y1, y1};
        float cws[4] = {wx0 * wy0, wx1 * wy0, wx0 * wy1, wx1 * wy1};
        for (int c = 0; c < 4; ++c) {
            int xi = cxs[c], yi = cys[c];
            bool valid = (xi >= 0) & (xi <= RES - 1) & (yi >= 0) & (yi <= RES - 1);
            int xc = min(max(xi, 0), RES - 1);
            int yc = min(max(yi, 0), RES - 1);
            float w = valid ? cws[c] : 0.0f;
            size_t texel = (size_t)yc * RES + xc;
#pragma unroll
            for (int k = 0; k < 8; ++k) {
                float v = C_mat[((size_t)p * CF + sub * 8 + k) * PLANE_ELEMS + texel];
                acc[k] += w * v;
            }
        }
    }

    float4* o = (float4*)(out + (size_t)n * CF + (size_t)sub * 8);
    o[0] = make_float4(acc[0], acc[1], acc[2], acc[3]);
    o[1] = make_float4(acc[4], acc[5], acc[6], acc[7]);
}

extern "C" void kernel_launch(void* const* d_in, const int* in_sizes, int n_in,
                              void* d_out, int out_size, void* d_ws, size_t ws_size,
                              hipStream_t stream) {
    const float* x     = (const float*)d_in[0];
    const float* C_mat = (const float*)d_in[1];
    float* out = (float*)d_out;
    int n_pts = in_sizes[0] / 3;

    size_t need = (size_t)3 * PLANE_ELEMS * CF * sizeof(__half);  // ~50.3 MB
    int sample_blocks = (n_pts * 4 + 255) / 256;

    if (ws_size >= need) {
        __half* planes = (__half*)d_ws;
        int tblocks = 3 * RES * (RES / TX);   // 3 * 512 * 4 = 6144
        triplane_transpose<<<tblocks, 256, 0, stream>>>(C_mat, planes);
        triplane_sample<<<sample_blocks, 256, 0, stream>>>(x, planes, out, n_pts);
    } else {
        triplane_sample_direct<<<sample_blocks, 256, 0, stream>>>(x, C_mat, out, n_pts);
    }
}